// Round 9
// baseline (192.044 us; speedup 1.0000x reference)
//
#include <hip/hip_runtime.h>
#include <hip/hip_bf16.h>

// Problem sizes (fixed): B=16, N_LOG=512, N_PHYS(Q)=2048, E=2048
#define BATCH 16
#define NLOG 512
#define Q 2048
#define NEDGE 2048
#define M_TOT (BATCH * NLOG)   // 8192 GEMM rows
#define KB 2048                // K bytes per row (fp8, 1 B/elem)

typedef float f32x4 __attribute__((ext_vector_type(4)));
typedef int i32x4 __attribute__((ext_vector_type(4)));
typedef int i32x8 __attribute__((ext_vector_type(8)));

__device__ __forceinline__ unsigned char to_e4m3(float f) {
    int pk = __builtin_amdgcn_cvt_pk_fp8_f32(f, f, 0, false);
    return (unsigned char)(pk & 0xff);
}

// ---------------------------------------------------------------------------
// K1 prep (grid 8192+4096+16):
//  blocks [0,8192): P fp32 -> P8 e4m3 (8 elem/thr, 8B packed stores)
//  blocks [8192,12288): A8t[q][p] = (d_hw[p][q]==1) e4m3, 32x32 LDS transpose
//  blocks [12288,12304): per-batch: sw[b] = sum_e w  AND scatter
//                        Wf32[b,src,dst] += w (Wf32 pre-zeroed by memset).
//                        Block 12288 zeroes total+counter.
__global__ __launch_bounds__(256) void prep(const float* __restrict__ P,
                                            unsigned char* __restrict__ P8,
                                            const int* __restrict__ d_hw,
                                            unsigned char* __restrict__ A8t,
                                            const int* __restrict__ esrc,
                                            const int* __restrict__ edst,
                                            const float* __restrict__ ew,
                                            float* __restrict__ Wf32,
                                            float* __restrict__ sw,
                                            float* __restrict__ total,
                                            unsigned* __restrict__ counter) {
    const int t = threadIdx.x;
    int bid = blockIdx.x;
    if (bid < 8192) {
        int i = (bid * 256 + t) * 8;
        float4 v0 = *(const float4*)(P + i);
        float4 v1 = *(const float4*)(P + i + 4);
        int lo = 0, hi = 0;
        lo = __builtin_amdgcn_cvt_pk_fp8_f32(v0.x, v0.y, lo, false);
        lo = __builtin_amdgcn_cvt_pk_fp8_f32(v0.z, v0.w, lo, true);
        hi = __builtin_amdgcn_cvt_pk_fp8_f32(v1.x, v1.y, hi, false);
        hi = __builtin_amdgcn_cvt_pk_fp8_f32(v1.z, v1.w, hi, true);
        int2 st; st.x = lo; st.y = hi;
        *(int2*)(P8 + i) = st;
    } else if (bid < 12288) {
        bid -= 8192;
        __shared__ unsigned char tile[32][33];
        int q0 = (bid & 63) * 32;
        int p0 = (bid >> 6) * 32;
        int tx = t & 31;
        int ty = t >> 5;  // 0..7
        for (int s = 0; s < 32; s += 8) {
            int p = p0 + ty + s;
            int v = d_hw[(size_t)p * Q + q0 + tx];
            tile[ty + s][tx] = (v == 1) ? 0x38 : 0x00;  // e4m3 1.0 / 0.0
        }
        __syncthreads();
        for (int s = 0; s < 32; s += 8) {
            A8t[(size_t)(q0 + ty + s) * Q + p0 + tx] = tile[tx][ty + s];
        }
    } else {
        int b = bid - 12288;
        if (b == 0 && t == 0) { *total = 0.f; *counter = 0u; }
        float s = 0.f;
        float* Wb = Wf32 + (size_t)b * NLOG * NLOG;
        #pragma unroll
        for (int k = 0; k < 8; k++) {
            int e = b * NEDGE + k * 256 + t;
            float wg = ew[e];
            s += wg;
            atomicAdd(&Wb[esrc[e] * NLOG + edst[e]], wg);
        }
        #pragma unroll
        for (int off = 32; off > 0; off >>= 1) s += __shfl_xor(s, off);
        __shared__ float red[4];
        if ((t & 63) == 0) red[t >> 6] = s;
        __syncthreads();
        if (t == 0) sw[b] = red[0] + red[1] + red[2] + red[3];
    }
}

// ---------------------------------------------------------------------------
// K2: main GEMM  PA[M,N] = P8[M,K] * A8t[N,K]^T  fp8-e4m3 via
// mfma_scale_f32_16x16x128_f8f6f4 (unit scales). 256x128 C-tile, 2x2 waves,
// wave = 8x4 MFMAs, BK=128B. XOR chunk swizzle phys = logical ^ (row&7).
// Output e4m3 of PA/256. VERBATIM R7 (measured 44 us, 1561 TF, 96% of the
// m148 fp8 plateau) — do not touch.
__global__ __launch_bounds__(256, 2) void gemm_bt8(const unsigned char* __restrict__ A,
                                                   const unsigned char* __restrict__ Bt,
                                                   unsigned char* __restrict__ PA8) {
    __shared__ unsigned char As[32768];  // 256 x 128
    __shared__ unsigned char Bs[16384];  // 128 x 128

    const int t = threadIdx.x;
    const int w = t >> 6;
    const int wr = w >> 1, wc = w & 1;
    const int l = t & 63;
    const int quad = l >> 4;
    const int lane16 = l & 15;

    const int m0 = blockIdx.x * 256;
    const int n0 = blockIdx.y * 128;

    const int s_row = t >> 3;                            // 0..31
    const int s_off = (((t & 7) ^ (s_row & 7)) << 4);    // swizzled src byte
    const int r7 = lane16 & 7;
    const int c0 = ((2 * quad) ^ r7) << 4;
    const int c1 = ((2 * quad + 1) ^ r7) << 4;

    f32x4 acc[8][4] = {};

    for (int k0 = 0; k0 < KB; k0 += 128) {
        #pragma unroll
        for (int c = 0; c < 8; c++) {
            const unsigned char* g = A + (size_t)(m0 + c * 32 + s_row) * KB + k0 + s_off;
            __builtin_amdgcn_global_load_lds(
                (const __attribute__((address_space(1))) void*)g,
                (__attribute__((address_space(3))) void*)(As + c * 4096 + w * 1024),
                16, 0, 0);
        }
        #pragma unroll
        for (int c = 0; c < 4; c++) {
            const unsigned char* g = Bt + (size_t)(n0 + c * 32 + s_row) * KB + k0 + s_off;
            __builtin_amdgcn_global_load_lds(
                (const __attribute__((address_space(1))) void*)g,
                (__attribute__((address_space(3))) void*)(Bs + c * 4096 + w * 1024),
                16, 0, 0);
        }
        __syncthreads();

        i32x8 bfr[4];
        #pragma unroll
        for (int j = 0; j < 4; j++) {
            int base = (wc * 64 + j * 16 + lane16) << 7;
            i32x4 lo = *(const i32x4*)(Bs + base + c0);
            i32x4 hi = *(const i32x4*)(Bs + base + c1);
            bfr[j] = __builtin_shufflevector(lo, hi, 0, 1, 2, 3, 4, 5, 6, 7);
        }
        #pragma unroll
        for (int i = 0; i < 8; i++) {
            int base = (wr * 128 + i * 16 + lane16) << 7;
            i32x4 lo = *(const i32x4*)(As + base + c0);
            i32x4 hi = *(const i32x4*)(As + base + c1);
            i32x8 af = __builtin_shufflevector(lo, hi, 0, 1, 2, 3, 4, 5, 6, 7);
            #pragma unroll
            for (int j = 0; j < 4; j++)
                acc[i][j] = __builtin_amdgcn_mfma_scale_f32_16x16x128_f8f6f4(
                    af, bfr[j], acc[i][j], 0, 0, 0, 127, 0, 127);
        }
        __syncthreads();
    }

    #pragma unroll
    for (int i = 0; i < 8; i++) {
        #pragma unroll
        for (int j = 0; j < 4; j++) {
            #pragma unroll
            for (int r = 0; r < 4; r++) {
                int row = m0 + wr * 128 + i * 16 + quad * 4 + r;
                int col = n0 + wc * 64 + j * 16 + lane16;
                PA8[(size_t)row * Q + col] = to_e4m3(acc[i][j][r] * (1.0f / 256.0f));
            }
        }
    }
}

// ---------------------------------------------------------------------------
// K3: score GEMM + fused W-dot + loss finalize.
//   X[i,j] = sum_q PA8_b[i,q] * P8_b[j,q]   (= (PA.P^T)/256 in fp32 acc)
//   part_b = sum_ij W_b[i,j] * X[i,j]  -> atomicAdd(total, part*256/(16*sw_b))
// 64(i) x 128(j) tile, grid (8,4,16) = 512 blocks (2/CU), 2x2 waves, wave =
// 2x4 MFMAs. K-loop verbatim R7 gemm_s8. Last block writes the loss. No S
// tensor, no edge pass, W stays exact fp32.
__global__ __launch_bounds__(256, 2) void gemm_sw(const unsigned char* __restrict__ PA8,
                                                  const unsigned char* __restrict__ P8,
                                                  const float* __restrict__ Wf32,
                                                  const float* __restrict__ sw,
                                                  float* __restrict__ total,
                                                  unsigned* __restrict__ counter,
                                                  float* __restrict__ out) {
    __shared__ unsigned char As[8192];   // 64 x 128
    __shared__ unsigned char Bs[16384];  // 128 x 128

    const int t = threadIdx.x;
    const int w = t >> 6;
    const int wr = w >> 1, wc = w & 1;
    const int l = t & 63;
    const int quad = l >> 4;
    const int lane16 = l & 15;

    const int b = blockIdx.z;
    const int m0 = blockIdx.x * 64;      // i
    const int n0 = blockIdx.y * 128;     // j
    const unsigned char* A  = PA8 + (size_t)b * NLOG * Q;
    const unsigned char* Bt = P8  + (size_t)b * NLOG * Q;
    const float* Wb = Wf32 + (size_t)b * NLOG * NLOG;

    const int s_row = t >> 3;
    const int s_off = (((t & 7) ^ (s_row & 7)) << 4);
    const int r7 = lane16 & 7;
    const int c0 = ((2 * quad) ^ r7) << 4;
    const int c1 = ((2 * quad + 1) ^ r7) << 4;

    f32x4 acc[2][4] = {};

    for (int k0 = 0; k0 < KB; k0 += 128) {
        #pragma unroll
        for (int c = 0; c < 2; c++) {
            const unsigned char* g = A + (size_t)(m0 + c * 32 + s_row) * KB + k0 + s_off;
            __builtin_amdgcn_global_load_lds(
                (const __attribute__((address_space(1))) void*)g,
                (__attribute__((address_space(3))) void*)(As + c * 4096 + w * 1024),
                16, 0, 0);
        }
        #pragma unroll
        for (int c = 0; c < 4; c++) {
            const unsigned char* g = Bt + (size_t)(n0 + c * 32 + s_row) * KB + k0 + s_off;
            __builtin_amdgcn_global_load_lds(
                (const __attribute__((address_space(1))) void*)g,
                (__attribute__((address_space(3))) void*)(Bs + c * 4096 + w * 1024),
                16, 0, 0);
        }
        __syncthreads();

        i32x8 bfr[4];
        #pragma unroll
        for (int j = 0; j < 4; j++) {
            int base = (wc * 64 + j * 16 + lane16) << 7;
            i32x4 lo = *(const i32x4*)(Bs + base + c0);
            i32x4 hi = *(const i32x4*)(Bs + base + c1);
            bfr[j] = __builtin_shufflevector(lo, hi, 0, 1, 2, 3, 4, 5, 6, 7);
        }
        #pragma unroll
        for (int i = 0; i < 2; i++) {
            int base = (wr * 32 + i * 16 + lane16) << 7;
            i32x4 lo = *(const i32x4*)(As + base + c0);
            i32x4 hi = *(const i32x4*)(As + base + c1);
            i32x8 af = __builtin_shufflevector(lo, hi, 0, 1, 2, 3, 4, 5, 6, 7);
            #pragma unroll
            for (int j = 0; j < 4; j++)
                acc[i][j] = __builtin_amdgcn_mfma_scale_f32_16x16x128_f8f6f4(
                    af, bfr[j], acc[i][j], 0, 0, 0, 127, 0, 127);
        }
        __syncthreads();
    }

    // fused W-dot epilogue: C/D layout col=lane16 (j), row=quad*4+r (i)
    float part = 0.f;
    #pragma unroll
    for (int i = 0; i < 2; i++) {
        #pragma unroll
        for (int r = 0; r < 4; r++) {
            int row = m0 + wr * 32 + i * 16 + quad * 4 + r;
            const float* wrow = Wb + (size_t)row * NLOG + n0 + wc * 64 + lane16;
            #pragma unroll
            for (int j = 0; j < 4; j++)
                part += wrow[j * 16] * acc[i][j][r];
        }
    }
    #pragma unroll
    for (int off = 32; off > 0; off >>= 1) part += __shfl_xor(part, off);
    __shared__ float red[4];
    if (l == 0) red[w] = part;
    __syncthreads();

    __shared__ unsigned done;
    if (t == 0) {
        // X = (PA.P^T)/256 -> adj_b = 256*part_b; loss sum needs /16
        float scale = 256.0f / (16.0f * fmaxf(sw[b], 1e-8f));
        atomicAdd(total, (red[0] + red[1] + red[2] + red[3]) * scale);
        __threadfence();
        done = atomicAdd(counter, 1u);
    }
    __syncthreads();
    if (t == 0 && done == 512 - 1) {
        __threadfence();
        out[0] = -atomicAdd(total, 0.0f);   // device-scope read
    }
}

// ---------------------------------------------------------------------------
extern "C" void kernel_launch(void* const* d_in, const int* in_sizes, int n_in,
                              void* d_out, int out_size, void* d_ws, size_t ws_size,
                              hipStream_t stream) {
    const float* P    = (const float*)d_in[0];
    const int* d_hw   = (const int*)d_in[1];
    const int* esrc   = (const int*)d_in[2];
    const int* edst   = (const int*)d_in[3];
    const float* ew   = (const float*)d_in[4];
    float* out        = (float*)d_out;

    char* ws = (char*)d_ws;
    // workspace layout (bytes), total ~54.5 MB:
    //   P8   : e4m3 [B*N][Q]   = 16,777,216   [0, 16.8M)
    //   A8t  : e4m3 [Q][Q]     =  4,194,304   [16.8M, 21.0M)
    //   PA8  : e4m3 [B*N][Q]   = 16,777,216   [21.0M, 37.7M)   (PA/256)
    //   Wf32 : f32  [B][N][N]  = 16,777,216   [37.7M, 54.5M)
    //   sw/total/counter at 54.5M
    unsigned char* P8  = (unsigned char*)ws;
    unsigned char* A8t = (unsigned char*)(ws + 16777216);
    unsigned char* PA8 = (unsigned char*)(ws + 20971520);
    float* Wf32        = (float*)(ws + 37748736);
    float* sw          = (float*)(ws + 54525952);
    float* total       = (float*)(ws + 54525952 + 64);
    unsigned* counter  = (unsigned*)(ws + 54525952 + 128);

    hipMemsetAsync(Wf32, 0, 16777216, stream);
    prep<<<8192 + 4096 + 16, 256, 0, stream>>>(P, P8, d_hw, A8t, esrc, edst, ew,
                                               Wf32, sw, total, counter);
    gemm_bt8<<<dim3(M_TOT / 256, Q / 128), 256, 0, stream>>>(P8, A8t, PA8);
    gemm_sw<<<dim3(NLOG / 64, NLOG / 128, BATCH), 256, 0, stream>>>(
        PA8, P8, Wf32, sw, total, counter, out);
}

// Round 10
// 183.908 us; speedup vs baseline: 1.0442x; 1.0442x over previous
//
#include <hip/hip_runtime.h>
#include <hip/hip_bf16.h>

// Problem sizes (fixed): B=16, N_LOG=512, N_PHYS(Q)=2048, E=2048
#define BATCH 16
#define NLOG 512
#define Q 2048
#define NEDGE 2048
#define M_TOT (BATCH * NLOG)   // 8192 GEMM rows
#define KB 2048                // K bytes per row (fp8, 1 B/elem)

typedef float f32x4 __attribute__((ext_vector_type(4)));
typedef int i32x4 __attribute__((ext_vector_type(4)));
typedef int i32x8 __attribute__((ext_vector_type(8)));

__device__ __forceinline__ unsigned char to_e4m3(float f) {
    int pk = __builtin_amdgcn_cvt_pk_fp8_f32(f, f, 0, false);
    return (unsigned char)(pk & 0xff);
}

// ---------------------------------------------------------------------------
// K1 prep (grid 8192 + 4096 + 128 + 16):
//  [0,8192):       P fp32 -> P8 e4m3 (8 elem/thr, 8B packed stores)
//  [8192,12288):   A8t[q][p] = (d_hw[p][q]==1) e4m3, 32x32 LDS transpose
//  [12288,12416):  W build, batch-private: block = (batch b, row-chunk c).
//                  Zero rows [c*64,(c+1)*64) of W_b (128 KB), sync, then scan
//                  all 2048 edges of batch b and scatter those with src in
//                  range (LDS-local atomics would also work; global is fine
//                  since the slice is block-private). No memset dispatch.
//  [12416,12432):  sw[b] = sum_e w. Block 12416 zeroes total+counter.
__global__ __launch_bounds__(256) void prep(const float* __restrict__ P,
                                            unsigned char* __restrict__ P8,
                                            const int* __restrict__ d_hw,
                                            unsigned char* __restrict__ A8t,
                                            const int* __restrict__ esrc,
                                            const int* __restrict__ edst,
                                            const float* __restrict__ ew,
                                            float* __restrict__ Wf32,
                                            float* __restrict__ sw,
                                            float* __restrict__ total,
                                            unsigned* __restrict__ counter) {
    const int t = threadIdx.x;
    int bid = blockIdx.x;
    if (bid < 8192) {
        int i = (bid * 256 + t) * 8;
        float4 v0 = *(const float4*)(P + i);
        float4 v1 = *(const float4*)(P + i + 4);
        int lo = 0, hi = 0;
        lo = __builtin_amdgcn_cvt_pk_fp8_f32(v0.x, v0.y, lo, false);
        lo = __builtin_amdgcn_cvt_pk_fp8_f32(v0.z, v0.w, lo, true);
        hi = __builtin_amdgcn_cvt_pk_fp8_f32(v1.x, v1.y, hi, false);
        hi = __builtin_amdgcn_cvt_pk_fp8_f32(v1.z, v1.w, hi, true);
        int2 st; st.x = lo; st.y = hi;
        *(int2*)(P8 + i) = st;
    } else if (bid < 12288) {
        bid -= 8192;
        __shared__ unsigned char tile[32][33];
        int q0 = (bid & 63) * 32;
        int p0 = (bid >> 6) * 32;
        int tx = t & 31;
        int ty = t >> 5;  // 0..7
        for (int s = 0; s < 32; s += 8) {
            int p = p0 + ty + s;
            int v = d_hw[(size_t)p * Q + q0 + tx];
            tile[ty + s][tx] = (v == 1) ? 0x38 : 0x00;  // e4m3 1.0 / 0.0
        }
        __syncthreads();
        for (int s = 0; s < 32; s += 8) {
            A8t[(size_t)(q0 + ty + s) * Q + p0 + tx] = tile[tx][ty + s];
        }
    } else if (bid < 12416) {
        int bb = bid - 12288;
        int b = bb >> 3;            // batch
        int c = bb & 7;             // row chunk: rows [c*64, c*64+64)
        float* Wb = Wf32 + (size_t)b * NLOG * NLOG;
        // zero this block's private 64-row slice (128 KB)
        float4 z = {0.f, 0.f, 0.f, 0.f};
        float* base = Wb + c * 64 * NLOG;
        #pragma unroll
        for (int s = 0; s < 32; s++)
            *(float4*)(base + (s * 256 + t) * 4) = z;
        __syncthreads();
        // scatter edges of batch b whose src is in [c*64, c*64+64)
        int lo = c * 64, hi = lo + 64;
        #pragma unroll
        for (int k = 0; k < 8; k++) {
            int e = b * NEDGE + k * 256 + t;
            int src = esrc[e];
            if (src >= lo && src < hi)
                atomicAdd(&Wb[src * NLOG + edst[e]], ew[e]);
        }
    } else {
        int b = bid - 12416;
        if (b == 0 && t == 0) { *total = 0.f; *counter = 0u; }
        float s = 0.f;
        #pragma unroll
        for (int k = 0; k < 8; k++) s += ew[b * NEDGE + k * 256 + t];
        #pragma unroll
        for (int off = 32; off > 0; off >>= 1) s += __shfl_xor(s, off);
        __shared__ float red[4];
        if ((t & 63) == 0) red[t >> 6] = s;
        __syncthreads();
        if (t == 0) sw[b] = red[0] + red[1] + red[2] + red[3];
    }
}

// ---------------------------------------------------------------------------
// K2: main GEMM  PA[M,N] = P8[M,K] * A8t[N,K]^T  fp8-e4m3 via
// mfma_scale_f32_16x16x128_f8f6f4 (unit scales). 256x128 C-tile, 2x2 waves,
// wave = 8x4 MFMAs, BK=128B. XOR chunk swizzle phys = logical ^ (row&7).
// Output e4m3 of PA/256. VERBATIM R7 (measured 44 us, 1561 TF) — do not touch.
__global__ __launch_bounds__(256, 2) void gemm_bt8(const unsigned char* __restrict__ A,
                                                   const unsigned char* __restrict__ Bt,
                                                   unsigned char* __restrict__ PA8) {
    __shared__ unsigned char As[32768];  // 256 x 128
    __shared__ unsigned char Bs[16384];  // 128 x 128

    const int t = threadIdx.x;
    const int w = t >> 6;
    const int wr = w >> 1, wc = w & 1;
    const int l = t & 63;
    const int quad = l >> 4;
    const int lane16 = l & 15;

    const int m0 = blockIdx.x * 256;
    const int n0 = blockIdx.y * 128;

    const int s_row = t >> 3;                            // 0..31
    const int s_off = (((t & 7) ^ (s_row & 7)) << 4);    // swizzled src byte
    const int r7 = lane16 & 7;
    const int c0 = ((2 * quad) ^ r7) << 4;
    const int c1 = ((2 * quad + 1) ^ r7) << 4;

    f32x4 acc[8][4] = {};

    for (int k0 = 0; k0 < KB; k0 += 128) {
        #pragma unroll
        for (int c = 0; c < 8; c++) {
            const unsigned char* g = A + (size_t)(m0 + c * 32 + s_row) * KB + k0 + s_off;
            __builtin_amdgcn_global_load_lds(
                (const __attribute__((address_space(1))) void*)g,
                (__attribute__((address_space(3))) void*)(As + c * 4096 + w * 1024),
                16, 0, 0);
        }
        #pragma unroll
        for (int c = 0; c < 4; c++) {
            const unsigned char* g = Bt + (size_t)(n0 + c * 32 + s_row) * KB + k0 + s_off;
            __builtin_amdgcn_global_load_lds(
                (const __attribute__((address_space(1))) void*)g,
                (__attribute__((address_space(3))) void*)(Bs + c * 4096 + w * 1024),
                16, 0, 0);
        }
        __syncthreads();

        i32x8 bfr[4];
        #pragma unroll
        for (int j = 0; j < 4; j++) {
            int base = (wc * 64 + j * 16 + lane16) << 7;
            i32x4 lo = *(const i32x4*)(Bs + base + c0);
            i32x4 hi = *(const i32x4*)(Bs + base + c1);
            bfr[j] = __builtin_shufflevector(lo, hi, 0, 1, 2, 3, 4, 5, 6, 7);
        }
        #pragma unroll
        for (int i = 0; i < 8; i++) {
            int base = (wr * 128 + i * 16 + lane16) << 7;
            i32x4 lo = *(const i32x4*)(As + base + c0);
            i32x4 hi = *(const i32x4*)(As + base + c1);
            i32x8 af = __builtin_shufflevector(lo, hi, 0, 1, 2, 3, 4, 5, 6, 7);
            #pragma unroll
            for (int j = 0; j < 4; j++)
                acc[i][j] = __builtin_amdgcn_mfma_scale_f32_16x16x128_f8f6f4(
                    af, bfr[j], acc[i][j], 0, 0, 0, 127, 0, 127);
        }
        __syncthreads();
    }

    #pragma unroll
    for (int i = 0; i < 8; i++) {
        #pragma unroll
        for (int j = 0; j < 4; j++) {
            #pragma unroll
            for (int r = 0; r < 4; r++) {
                int row = m0 + wr * 128 + i * 16 + quad * 4 + r;
                int col = n0 + wc * 64 + j * 16 + lane16;
                PA8[(size_t)row * Q + col] = to_e4m3(acc[i][j][r] * (1.0f / 256.0f));
            }
        }
    }
}

// ---------------------------------------------------------------------------
// K3: score GEMM + fused W-dot + loss finalize, reshaped vs R9:
// 128(i) x 128(j) tile, SPLIT-K x2 (scalar output -> split-K free via the
// existing atomic), 2x2 waves, wave = 4x4 MFMAs (MFMA:ds_read = 16/8 = 2.0
// vs R9's 1.33 — the measured LDS-BW bottleneck). Grid (4,4,32) = 512
// blocks, 2/CU. Last block writes the loss. No S tensor, no edge pass.
__global__ __launch_bounds__(256, 2) void gemm_sw(const unsigned char* __restrict__ PA8,
                                                  const unsigned char* __restrict__ P8,
                                                  const float* __restrict__ Wf32,
                                                  const float* __restrict__ sw,
                                                  float* __restrict__ total,
                                                  unsigned* __restrict__ counter,
                                                  float* __restrict__ out) {
    __shared__ unsigned char As[16384];  // 128 x 128
    __shared__ unsigned char Bs[16384];  // 128 x 128

    const int t = threadIdx.x;
    const int w = t >> 6;
    const int wr = w >> 1, wc = w & 1;
    const int l = t & 63;
    const int quad = l >> 4;
    const int lane16 = l & 15;

    const int b  = blockIdx.z >> 1;       // batch
    const int kh = blockIdx.z & 1;        // K-half
    const int m0 = blockIdx.x * 128;      // i
    const int n0 = blockIdx.y * 128;      // j
    const unsigned char* A  = PA8 + (size_t)b * NLOG * Q;
    const unsigned char* Bt = P8  + (size_t)b * NLOG * Q;
    const float* Wb = Wf32 + (size_t)b * NLOG * NLOG;

    const int s_row = t >> 3;
    const int s_off = (((t & 7) ^ (s_row & 7)) << 4);
    const int r7 = lane16 & 7;
    const int c0 = ((2 * quad) ^ r7) << 4;
    const int c1 = ((2 * quad + 1) ^ r7) << 4;

    f32x4 acc[4][4] = {};

    for (int k0 = kh * 1024; k0 < kh * 1024 + 1024; k0 += 128) {
        #pragma unroll
        for (int c = 0; c < 4; c++) {
            const unsigned char* g = A + (size_t)(m0 + c * 32 + s_row) * KB + k0 + s_off;
            __builtin_amdgcn_global_load_lds(
                (const __attribute__((address_space(1))) void*)g,
                (__attribute__((address_space(3))) void*)(As + c * 4096 + w * 1024),
                16, 0, 0);
        }
        #pragma unroll
        for (int c = 0; c < 4; c++) {
            const unsigned char* g = Bt + (size_t)(n0 + c * 32 + s_row) * KB + k0 + s_off;
            __builtin_amdgcn_global_load_lds(
                (const __attribute__((address_space(1))) void*)g,
                (__attribute__((address_space(3))) void*)(Bs + c * 4096 + w * 1024),
                16, 0, 0);
        }
        __syncthreads();

        i32x8 bfr[4];
        #pragma unroll
        for (int j = 0; j < 4; j++) {
            int base = (wc * 64 + j * 16 + lane16) << 7;
            i32x4 lo = *(const i32x4*)(Bs + base + c0);
            i32x4 hi = *(const i32x4*)(Bs + base + c1);
            bfr[j] = __builtin_shufflevector(lo, hi, 0, 1, 2, 3, 4, 5, 6, 7);
        }
        #pragma unroll
        for (int i = 0; i < 4; i++) {
            int base = (wr * 64 + i * 16 + lane16) << 7;
            i32x4 lo = *(const i32x4*)(As + base + c0);
            i32x4 hi = *(const i32x4*)(As + base + c1);
            i32x8 af = __builtin_shufflevector(lo, hi, 0, 1, 2, 3, 4, 5, 6, 7);
            #pragma unroll
            for (int j = 0; j < 4; j++)
                acc[i][j] = __builtin_amdgcn_mfma_scale_f32_16x16x128_f8f6f4(
                    af, bfr[j], acc[i][j], 0, 0, 0, 127, 0, 127);
        }
        __syncthreads();
    }

    // fused W-dot epilogue: C/D layout col=lane16 (j), row=quad*4+r (i)
    float part = 0.f;
    #pragma unroll
    for (int i = 0; i < 4; i++) {
        #pragma unroll
        for (int r = 0; r < 4; r++) {
            int row = m0 + wr * 64 + i * 16 + quad * 4 + r;
            const float* wrow = Wb + (size_t)row * NLOG + n0 + wc * 64 + lane16;
            #pragma unroll
            for (int j = 0; j < 4; j++)
                part += wrow[j * 16] * acc[i][j][r];
        }
    }
    #pragma unroll
    for (int off = 32; off > 0; off >>= 1) part += __shfl_xor(part, off);
    __shared__ float red[4];
    if (l == 0) red[w] = part;
    __syncthreads();

    __shared__ unsigned done;
    if (t == 0) {
        // X = (PA.P^T)/256 -> adj_b = 256*part_b; loss sum needs /16
        float scale = 256.0f / (16.0f * fmaxf(sw[b], 1e-8f));
        atomicAdd(total, (red[0] + red[1] + red[2] + red[3]) * scale);
        __threadfence();
        done = atomicAdd(counter, 1u);
    }
    __syncthreads();
    if (t == 0 && done == 512 - 1) {
        __threadfence();
        out[0] = -atomicAdd(total, 0.0f);   // device-scope read
    }
}

// ---------------------------------------------------------------------------
extern "C" void kernel_launch(void* const* d_in, const int* in_sizes, int n_in,
                              void* d_out, int out_size, void* d_ws, size_t ws_size,
                              hipStream_t stream) {
    const float* P    = (const float*)d_in[0];
    const int* d_hw   = (const int*)d_in[1];
    const int* esrc   = (const int*)d_in[2];
    const int* edst   = (const int*)d_in[3];
    const float* ew   = (const float*)d_in[4];
    float* out        = (float*)d_out;

    char* ws = (char*)d_ws;
    // workspace layout (bytes), total ~54.5 MB:
    //   P8   : e4m3 [B*N][Q]   = 16,777,216   [0, 16.8M)
    //   A8t  : e4m3 [Q][Q]     =  4,194,304   [16.8M, 21.0M)
    //   PA8  : e4m3 [B*N][Q]   = 16,777,216   [21.0M, 37.7M)   (PA/256)
    //   Wf32 : f32  [B][N][N]  = 16,777,216   [37.7M, 54.5M)
    //   sw/total/counter at 54.5M
    unsigned char* P8  = (unsigned char*)ws;
    unsigned char* A8t = (unsigned char*)(ws + 16777216);
    unsigned char* PA8 = (unsigned char*)(ws + 20971520);
    float* Wf32        = (float*)(ws + 37748736);
    float* sw          = (float*)(ws + 54525952);
    float* total       = (float*)(ws + 54525952 + 64);
    unsigned* counter  = (unsigned*)(ws + 54525952 + 128);

    prep<<<8192 + 4096 + 128 + 16, 256, 0, stream>>>(P, P8, d_hw, A8t, esrc,
                                                     edst, ew, Wf32, sw,
                                                     total, counter);
    gemm_bt8<<<dim3(M_TOT / 256, Q / 128), 256, 0, stream>>>(P8, A8t, PA8);
    gemm_sw<<<dim3(NLOG / 128, NLOG / 128, BATCH * 2), 256, 0, stream>>>(
        PA8, P8, Wf32, sw, total, counter, out);
}